// Round 5
// baseline (106.618 us; speedup 1.0000x reference)
//
#include <hip/hip_runtime.h>

// ModelInverse: invert monotone MLP CDF F(x) for 2M targets.
// Strategy: F is sample-independent -> tabulate A(x) on a coarse x-grid,
// build inverse table G on a fine uniform z-grid, per-sample lerp lookup.
//
// R5 key change: forward table shrunk 2^16 -> 2^13 cells. Error analysis:
// absmax (0.0039) is set by the INVERSE grid in flat regions
// ((1/KSZ)/(2*F'min), F'min ~ 2e-3); the forward table's lerp error is
// h^2*|F''|/(8|F'|) ~ 1e-8 at 2^16 -- massively over-resolved. 2^13 keeps
// forward-side error (<~4e-5, eval-noise-limited in flat cells) far below
// the z-grid floor while cutting build_table's 2.7e8-FMA cost 8x and making
// T fully L1-resident (32 KB) for the binary search.
//
// ws layout (floats): WE2[4096] | WE1[64] | WE3[64] | T[TSZ+1] | G[KSZ+1]

#define MONO 1e-3f
#define TLOG2 13
#define TSZ (1 << TLOG2)   // forward table: T[0..TSZ]
#define KLOG2 16
#define KSZ (1 << KLOG2)   // inverse table: G[0..KSZ]

#define WS_WE2 0
#define WS_WE1 4096
#define WS_WE3 (4096 + 64)
#define WS_T   (4096 + 128)
#define WS_G   (WS_T + TSZ + 1)

typedef float fvec64 __attribute__((ext_vector_type(64)));

__device__ __forceinline__ float fast_rcp(float x) {
#if __has_builtin(__builtin_amdgcn_rcpf)
    return __builtin_amdgcn_rcpf(x);   // v_rcp_f32, ~1 ulp
#else
    return 1.0f / x;
#endif
}

__device__ __forceinline__ float sigmoidf_(float t) {
    return fast_rcp(1.0f + __expf(-t));   // v_mul+v_exp+v_add+v_rcp
}

__global__ __launch_bounds__(256) void exp_weights_kernel(
        const float* __restrict__ pw1,
        const float* __restrict__ pw2,
        const float* __restrict__ pw3,
        float* __restrict__ ws) {
    int i = blockIdx.x * blockDim.x + threadIdx.x;
    if (i < 4096) ws[WS_WE2 + i] = expf(pw2[i]);
    if (i < 64) {
        ws[WS_WE1 + i] = expf(pw1[i]);  // pre_w1 is (64,1) flat
        ws[WS_WE3 + i] = expf(pw3[i]);  // pre_w3 is (1,64) flat
    }
}

// T[j] = sigmoid(w3 . sigmoid(W2 . sigmoid(x*w1+b1) + b2) + b3) + MONO*x
// Block = 256 threads = 4 waves; wave `sub` handles rows [16*sub, 16*sub+16)
// for 64 entries (lane = entry). Partials combined through LDS.
__global__ __launch_bounds__(256, 4) void build_table_kernel(
        const float* __restrict__ b1,
        const float* __restrict__ b2,
        const float* __restrict__ b3,
        const float* __restrict__ ws,
        float* __restrict__ T) {
    const float* __restrict__ WE2 = ws + WS_WE2;
    const float* __restrict__ WE1 = ws + WS_WE1;
    const float* __restrict__ WE3 = ws + WS_WE3;

    int tid  = threadIdx.x;
    int lane = tid & 63;
    // Wave-uniform; readfirstlane pins it to an SGPR so weight addressing is
    // provably scalar (s_load).
    int sub = __builtin_amdgcn_readfirstlane(tid >> 6);   // 0..3
    int j = blockIdx.x * 64 + lane;
    int jc = j <= TSZ ? j : TSZ;       // clamp; store is guarded below
    float x = (float)jc * (1.0f / (float)TSZ);

    // h1 as an SSA vector value: cannot be demoted to scratch or remat'd.
    fvec64 h1;
#pragma unroll
    for (int k = 0; k < 64; ++k)
        h1[k] = sigmoidf_(fmaf(x, WE1[k], b1[k]));

    const float* __restrict__ w2base = WE2 + sub * (16 * 64);
    const float* __restrict__ b2base = b2 + sub * 16;
    const float* __restrict__ w3base = WE3 + sub * 16;
    float acc3 = 0.0f;
#pragma unroll
    for (int r = 0; r < 16; ++r) {     // r const, sub SGPR -> s_load rows
        float acc = b2base[r];
        const float* __restrict__ wrow = w2base + r * 64;
#pragma unroll
        for (int jj = 0; jj < 64; ++jj)
            acc = fmaf(wrow[jj], h1[jj], acc);
        acc3 = fmaf(w3base[r], sigmoidf_(acc), acc3);
    }

    __shared__ float part[256];
    part[sub * 64 + lane] = acc3;
    __syncthreads();
    if (tid < 64 && j <= TSZ) {
        float s = part[lane] + part[64 + lane] + part[128 + lane]
                + part[192 + lane] + b3[0];
        T[j] = sigmoidf_(s) + MONO * x;
    }
}

// G[k] = x such that F(x) = k/KSZ, via binary search in T + in-cell lerp.
// T is 32 KB -> L1-resident; 13 dependent loads.
__global__ __launch_bounds__(256) void invert_table_kernel(
        const float* __restrict__ T,
        float* __restrict__ G) {
    int k = blockIdx.x * blockDim.x + threadIdx.x;
    if (k > KSZ) return;
    float a0 = T[0];
    float a1 = T[TSZ];
    float zt = fmaf((float)k * (1.0f / (float)KSZ), a1 - a0, a0);

    int lo = 0;
#pragma unroll
    for (int s = TSZ >> 1; s >= 1; s >>= 1) {
        int cand = lo + s;             // cand <= TSZ-1 always
        if (T[cand] <= zt) lo = cand;
    }
    float tl = T[lo];
    float th = T[lo + 1];
    float d = th - tl;
    float t = (d > 1e-30f) ? (zt - tl) / d : 0.5f;
    t = fminf(fmaxf(t, 0.0f), 1.0f);
    G[k] = ((float)lo + t) * (1.0f / (float)TSZ);
}

__device__ __forceinline__ float apply_one(float zv, const float* __restrict__ G) {
    float u = zv * (float)KSZ;
    u = fminf(fmaxf(u, 0.0f), (float)KSZ);
    int k = (int)u;
    if (k > KSZ - 1) k = KSZ - 1;
    float frac = u - (float)k;
    float g0 = G[k];
    float g1 = G[k + 1];
    return fmaf(frac, g1 - g0, g0);
}

__global__ __launch_bounds__(256) void apply_kernel(
        const float* __restrict__ z,
        const float* __restrict__ G,
        float* __restrict__ out, int n) {
    int i = blockIdx.x * blockDim.x + threadIdx.x;
    int base = i * 4;
    if (base + 3 < n) {
        float4 zz = *reinterpret_cast<const float4*>(z + base);
        float4 oo;
        oo.x = apply_one(zz.x, G);
        oo.y = apply_one(zz.y, G);
        oo.z = apply_one(zz.z, G);
        oo.w = apply_one(zz.w, G);
        *reinterpret_cast<float4*>(out + base) = oo;
    } else {
        for (int t = base; t < n; ++t)
            out[t] = apply_one(z[t], G);
    }
}

extern "C" void kernel_launch(void* const* d_in, const int* in_sizes, int n_in,
                              void* d_out, int out_size, void* d_ws, size_t ws_size,
                              hipStream_t stream) {
    const float* z   = (const float*)d_in[0];
    const float* pw1 = (const float*)d_in[1];
    const float* b1  = (const float*)d_in[2];
    const float* pw2 = (const float*)d_in[3];
    const float* b2  = (const float*)d_in[4];
    const float* pw3 = (const float*)d_in[5];
    const float* b3  = (const float*)d_in[6];
    float* out = (float*)d_out;
    float* ws  = (float*)d_ws;
    int n = in_sizes[0];

    exp_weights_kernel<<<16, 256, 0, stream>>>(pw1, pw2, pw3, ws);
    build_table_kernel<<<(TSZ + 1 + 63) / 64, 256, 0, stream>>>(
        b1, b2, b3, ws, ws + WS_T);
    invert_table_kernel<<<(KSZ + 1 + 255) / 256, 256, 0, stream>>>(
        ws + WS_T, ws + WS_G);
    int nv = (n + 3) / 4;
    apply_kernel<<<(nv + 255) / 256, 256, 0, stream>>>(z, ws + WS_G, out, n);
}

// Round 6
// 99.873 us; speedup vs baseline: 1.0675x; 1.0675x over previous
//
#include <hip/hip_runtime.h>

// ModelInverse: invert monotone MLP CDF F(x) for 2M targets.
// R6: 2-dispatch pipeline (was 4).
//  - fused_build: stages exp(pw2) into LDS per-block (kills exp_weights
//    kernel + cold cross-kernel weight reads through the L2-flushed /
//    poison-evicted cache hierarchy). W2 rows read as wave-uniform
//    ds_read_b128 broadcasts. T = A(j/TSZ) on 2^13+1 grid.
//  - fused_apply: stages T (32 KB) into LDS, 13-step binary search per
//    sample + in-cell lerp. No inverse table G, no invert dispatch, no L2
//    gather. Also removes the z-grid quantization that set absmax=0.0039.
//
// ws layout (floats): T[TSZ+1] only.

#define MONO 1e-3f
#define TLOG2 13
#define TSZ (1 << TLOG2)   // forward table: T[0..TSZ]

typedef float fvec64 __attribute__((ext_vector_type(64)));

__device__ __forceinline__ float fast_rcp(float x) {
#if __has_builtin(__builtin_amdgcn_rcpf)
    return __builtin_amdgcn_rcpf(x);   // v_rcp_f32, ~1 ulp
#else
    return 1.0f / x;
#endif
}

__device__ __forceinline__ float sigmoidf_(float t) {
    return fast_rcp(1.0f + __expf(-t));   // v_mul+v_exp+v_add+v_rcp
}

// T[j] = sigmoid(w3 . sigmoid(W2 . sigmoid(x*w1+b1) + b2) + b3) + MONO*x
// Block = 256 = 4 waves; wave `sub` handles rows [16*sub, 16*sub+16) for 64
// entries (lane = entry). exp(pw2) staged into LDS by the whole block.
__global__ __launch_bounds__(256, 4) void fused_build_kernel(
        const float* __restrict__ pw1,
        const float* __restrict__ b1,
        const float* __restrict__ pw2,
        const float* __restrict__ b2,
        const float* __restrict__ pw3,
        const float* __restrict__ b3,
        float* __restrict__ T) {
    __shared__ __align__(16) float W2s[4096];
    __shared__ float part[256];

    int tid  = threadIdx.x;
    // Stage exp(pw2) into LDS (coalesced input read; no dependence on any
    // prior kernel of ours).
#pragma unroll
    for (int i = 0; i < 16; ++i) {
        int idx = tid + i * 256;
        W2s[idx] = __expf(pw2[idx]);
    }
    __syncthreads();

    int lane = tid & 63;
    // Wave-uniform; pin to SGPR so LDS row addressing is provably uniform.
    int sub = __builtin_amdgcn_readfirstlane(tid >> 6);   // 0..3
    int j = blockIdx.x * 64 + lane;
    int jc = j <= TSZ ? j : TSZ;       // clamp; store guarded below
    float x = (float)jc * (1.0f / (float)TSZ);

    // h1 as an SSA vector value: cannot be demoted to scratch or remat'd.
    // pw1/b1 are wave-uniform addresses -> s_load; exp done in VALU.
    fvec64 h1;
#pragma unroll
    for (int k = 0; k < 64; ++k)
        h1[k] = sigmoidf_(fmaf(x, __expf(pw1[k]), b1[k]));

    float acc3 = 0.0f;
#pragma unroll
    for (int r = 0; r < 16; ++r) {
        int row = sub * 16 + r;        // SGPR + const -> uniform
        float acc = b2[row];
        const float4* __restrict__ w4 =
            reinterpret_cast<const float4*>(&W2s[row * 64]);
#pragma unroll
        for (int q = 0; q < 16; ++q) { // ds_read_b128, broadcast
            float4 w = w4[q];
            acc = fmaf(w.x, h1[4 * q + 0], acc);
            acc = fmaf(w.y, h1[4 * q + 1], acc);
            acc = fmaf(w.z, h1[4 * q + 2], acc);
            acc = fmaf(w.w, h1[4 * q + 3], acc);
        }
        acc3 = fmaf(__expf(pw3[row]), sigmoidf_(acc), acc3);
    }

    part[sub * 64 + lane] = acc3;
    __syncthreads();
    if (tid < 64 && j <= TSZ) {
        float s = part[lane] + part[64 + lane] + part[128 + lane]
                + part[192 + lane] + b3[0];
        T[j] = sigmoidf_(s) + MONO * x;
    }
}

// Per-sample: zt = a0 + z*(a1-a0); binary search T in LDS; lerp inside cell.
__device__ __forceinline__ float search_one(float zv, const float* Ts,
                                            float a0, float scale) {
    float zt = fmaf(zv, scale, a0);
    int lo = 0;
#pragma unroll
    for (int s = TSZ >> 1; s >= 1; s >>= 1) {
        int c = lo + s;                 // c <= TSZ-1 always
        lo = (Ts[c] <= zt) ? c : lo;
    }
    float tl = Ts[lo];
    float th = Ts[lo + 1];
    float d = th - tl;
    float t = (d > 1e-30f) ? (zt - tl) * fast_rcp(d) : 0.5f;
    t = fminf(fmaxf(t, 0.0f), 1.0f);
    return ((float)lo + t) * (1.0f / (float)TSZ);
}

#define APPLY_BLOCKS 512

__global__ __launch_bounds__(256) void fused_apply_kernel(
        const float* __restrict__ z,
        const float* __restrict__ T,
        float* __restrict__ out, int n) {
    __shared__ __align__(16) float Ts[TSZ + 1];
    int tid = threadIdx.x;
#pragma unroll
    for (int i = 0; i < (TSZ / 4) / 256; ++i) {   // 2048 float4s
        int idx = tid + i * 256;
        reinterpret_cast<float4*>(Ts)[idx] =
            reinterpret_cast<const float4*>(T)[idx];
    }
    if (tid == 0) Ts[TSZ] = T[TSZ];
    __syncthreads();

    float a0 = Ts[0];
    float scale = Ts[TSZ] - a0;

    int nv = n >> 2;
    int stride = gridDim.x * 256;
    for (int idx = blockIdx.x * 256 + tid; idx < nv; idx += stride) {
        float4 zz = reinterpret_cast<const float4*>(z)[idx];
        float4 oo;
        oo.x = search_one(zz.x, Ts, a0, scale);
        oo.y = search_one(zz.y, Ts, a0, scale);
        oo.z = search_one(zz.z, Ts, a0, scale);
        oo.w = search_one(zz.w, Ts, a0, scale);
        reinterpret_cast<float4*>(out)[idx] = oo;
    }
    // tail (n not multiple of 4)
    int base = nv * 4;
    for (int t = base + blockIdx.x * 256 + tid; t < n; t += stride)
        out[t] = search_one(z[t], Ts, a0, scale);
}

extern "C" void kernel_launch(void* const* d_in, const int* in_sizes, int n_in,
                              void* d_out, int out_size, void* d_ws, size_t ws_size,
                              hipStream_t stream) {
    const float* z   = (const float*)d_in[0];
    const float* pw1 = (const float*)d_in[1];
    const float* b1  = (const float*)d_in[2];
    const float* pw2 = (const float*)d_in[3];
    const float* b2  = (const float*)d_in[4];
    const float* pw3 = (const float*)d_in[5];
    const float* b3  = (const float*)d_in[6];
    float* out = (float*)d_out;
    float* T   = (float*)d_ws;
    int n = in_sizes[0];

    fused_build_kernel<<<(TSZ + 1 + 63) / 64, 256, 0, stream>>>(
        pw1, b1, pw2, b2, pw3, b3, T);
    fused_apply_kernel<<<APPLY_BLOCKS, 256, 0, stream>>>(z, T, out, n);
}

// Round 7
// 89.888 us; speedup vs baseline: 1.1861x; 1.1111x over previous
//
#include <hip/hip_runtime.h>

// ModelInverse: invert monotone MLP CDF F(x) for 2M targets.
// R7: bucket-accelerated inverse search (3 dispatches).
//  - fused_build: T[j] = A(j/TSZ) on 2^13+1 grid (unchanged from R6).
//  - build_idx:   IDX[k] = max{j : T[j] <= zb_k} for B=8192 uniform z-buckets
//                 (u16, 16 KB) -- trivial 8K-thread dispatch on L2-hot T.
//  - bucket_apply: stage T (32 KB) + IDX (16 KB) in LDS. Per sample: bucket
//                 lookup gives [lo,hi] with span avg ~2 cells; short binary
//                 search + fix-up (reuses lerp reads) -> ~5-6 LDS ops/sample
//                 vs 15 for the full 13-step search. Fix-up makes the final
//                 cell identical to R6's search -> bit-identical output.
//
// ws layout: T[TSZ+1] floats @0 | IDX[8200] u16 after (u32/uint4-aligned).

#define MONO 1e-3f
#define TLOG2 13
#define TSZ (1 << TLOG2)   // forward table: T[0..TSZ]
#define BLOG2 13
#define BSZ (1 << BLOG2)   // z-bucket count
#define IDXN 8200          // u16 slots incl. pad to uint4 multiple (16400 B)

typedef float fvec64 __attribute__((ext_vector_type(64)));

__device__ __forceinline__ float fast_rcp(float x) {
#if __has_builtin(__builtin_amdgcn_rcpf)
    return __builtin_amdgcn_rcpf(x);   // v_rcp_f32, ~1 ulp
#else
    return 1.0f / x;
#endif
}

__device__ __forceinline__ float sigmoidf_(float t) {
    return fast_rcp(1.0f + __expf(-t));   // v_mul+v_exp+v_add+v_rcp
}

// T[j] = sigmoid(w3 . sigmoid(W2 . sigmoid(x*w1+b1) + b2) + b3) + MONO*x
// Block = 256 = 4 waves; wave `sub` handles rows [16*sub, 16*sub+16) for 64
// entries (lane = entry). exp(pw2) staged into LDS by the whole block.
__global__ __launch_bounds__(256, 4) void fused_build_kernel(
        const float* __restrict__ pw1,
        const float* __restrict__ b1,
        const float* __restrict__ pw2,
        const float* __restrict__ b2,
        const float* __restrict__ pw3,
        const float* __restrict__ b3,
        float* __restrict__ T) {
    __shared__ __align__(16) float W2s[4096];
    __shared__ float part[256];

    int tid  = threadIdx.x;
#pragma unroll
    for (int i = 0; i < 16; ++i) {
        int idx = tid + i * 256;
        W2s[idx] = __expf(pw2[idx]);
    }
    __syncthreads();

    int lane = tid & 63;
    int sub = __builtin_amdgcn_readfirstlane(tid >> 6);   // 0..3, SGPR
    int j = blockIdx.x * 64 + lane;
    int jc = j <= TSZ ? j : TSZ;
    float x = (float)jc * (1.0f / (float)TSZ);

    fvec64 h1;    // SSA vector: cannot be demoted/remat'd
#pragma unroll
    for (int k = 0; k < 64; ++k)
        h1[k] = sigmoidf_(fmaf(x, __expf(pw1[k]), b1[k]));

    float acc3 = 0.0f;
#pragma unroll
    for (int r = 0; r < 16; ++r) {
        int row = sub * 16 + r;        // uniform -> s_load / uniform ds addr
        float acc = b2[row];
        const float4* __restrict__ w4 =
            reinterpret_cast<const float4*>(&W2s[row * 64]);
#pragma unroll
        for (int q = 0; q < 16; ++q) { // ds_read_b128 broadcast
            float4 w = w4[q];
            acc = fmaf(w.x, h1[4 * q + 0], acc);
            acc = fmaf(w.y, h1[4 * q + 1], acc);
            acc = fmaf(w.z, h1[4 * q + 2], acc);
            acc = fmaf(w.w, h1[4 * q + 3], acc);
        }
        acc3 = fmaf(__expf(pw3[row]), sigmoidf_(acc), acc3);
    }

    part[sub * 64 + lane] = acc3;
    __syncthreads();
    if (tid < 64 && j <= TSZ) {
        float s = part[lane] + part[64 + lane] + part[128 + lane]
                + part[192 + lane] + b3[0];
        T[j] = sigmoidf_(s) + MONO * x;
    }
}

// IDX[k] = max{j in [0,TSZ]: T[j] <= zb_k}, zb_k = a0 + (k/BSZ)*(a1-a0).
__global__ __launch_bounds__(256) void build_idx_kernel(
        const float* __restrict__ T,
        unsigned short* __restrict__ IDX) {
    int k = blockIdx.x * blockDim.x + threadIdx.x;
    if (k > BSZ) return;
    float a0 = T[0];
    float a1 = T[TSZ];
    float zb = fmaf((float)k * (1.0f / (float)BSZ), a1 - a0, a0);
    int lo = 0;
#pragma unroll
    for (int s = TSZ >> 1; s >= 1; s >>= 1) {
        int c = lo + s;                // c <= TSZ-1
        if (T[c] <= zb) lo = c;
    }
    if (T[TSZ] <= zb) lo = TSZ;        // k == BSZ boundary
    IDX[k] = (unsigned short)lo;
}

// Per-sample inverse: bucket -> [lo,hi] window -> short search -> fix-up ->
// lerp. Fix-up makes the final cell exactly max{j: T[j] <= zt}.
__device__ __forceinline__ float search_one(float zv, const float* Ts,
                                            const unsigned short* IDXs,
                                            float a0, float scale, float bscale) {
    float zt = fmaf(zv, scale, a0);
    int k = (int)((zt - a0) * bscale);
    k = k < 0 ? 0 : (k > BSZ - 1 ? BSZ - 1 : k);
    int lo = IDXs[k];
    int hi = IDXs[k + 1];
    if (hi > TSZ - 1) hi = TSZ - 1;
    while (hi > lo) {                  // span avg ~2 -> ~1 iteration
        int mid = (lo + hi + 1) >> 1;
        if (Ts[mid] <= zt) lo = mid; else hi = mid - 1;
    }
    float tl = Ts[lo];
    float th = Ts[lo + 1];
    // rounding fix-up (rarely taken; reuses lerp operands)
    while (tl > zt && lo > 0)          { --lo; th = tl; tl = Ts[lo]; }
    while (th <= zt && lo < TSZ - 1)   { ++lo; tl = th; th = Ts[lo + 1]; }
    float d = th - tl;
    float t = (d > 1e-30f) ? (zt - tl) * fast_rcp(d) : 0.5f;
    t = fminf(fmaxf(t, 0.0f), 1.0f);
    return ((float)lo + t) * (1.0f / (float)TSZ);
}

#define APPLY_BLOCKS 768   // 49.2 KB LDS -> 3 blocks/CU, 768 = 3x256 CUs

__global__ __launch_bounds__(256) void bucket_apply_kernel(
        const float* __restrict__ z,
        const float* __restrict__ T,
        const unsigned short* __restrict__ IDX,
        float* __restrict__ out, int n) {
    __shared__ __align__(16) float Ts[TSZ + 1];
    __shared__ __align__(16) unsigned short IDXs[IDXN];
    int tid = threadIdx.x;
#pragma unroll
    for (int i = 0; i < (TSZ / 4) / 256; ++i) {      // 2048 float4s
        int idx = tid + i * 256;
        reinterpret_cast<float4*>(Ts)[idx] =
            reinterpret_cast<const float4*>(T)[idx];
    }
    // 16400 B of IDX = 1025 uint4s
    for (int idx = tid; idx < IDXN / 8; idx += 256) {
        reinterpret_cast<uint4*>(IDXs)[idx] =
            reinterpret_cast<const uint4*>(IDX)[idx];
    }
    if (tid == 0) Ts[TSZ] = T[TSZ];
    __syncthreads();

    float a0 = Ts[0];
    float scale = Ts[TSZ] - a0;
    float bscale = (float)BSZ * fast_rcp(scale);

    int nv = n >> 2;
    int stride = gridDim.x * 256;
    for (int idx = blockIdx.x * 256 + tid; idx < nv; idx += stride) {
        float4 zz = reinterpret_cast<const float4*>(z)[idx];
        float4 oo;
        oo.x = search_one(zz.x, Ts, IDXs, a0, scale, bscale);
        oo.y = search_one(zz.y, Ts, IDXs, a0, scale, bscale);
        oo.z = search_one(zz.z, Ts, IDXs, a0, scale, bscale);
        oo.w = search_one(zz.w, Ts, IDXs, a0, scale, bscale);
        reinterpret_cast<float4*>(out)[idx] = oo;
    }
    int base = nv * 4;
    for (int t = base + blockIdx.x * 256 + tid; t < n; t += stride)
        out[t] = search_one(z[t], Ts, IDXs, a0, scale, bscale);
}

extern "C" void kernel_launch(void* const* d_in, const int* in_sizes, int n_in,
                              void* d_out, int out_size, void* d_ws, size_t ws_size,
                              hipStream_t stream) {
    const float* z   = (const float*)d_in[0];
    const float* pw1 = (const float*)d_in[1];
    const float* b1  = (const float*)d_in[2];
    const float* pw2 = (const float*)d_in[3];
    const float* b2  = (const float*)d_in[4];
    const float* pw3 = (const float*)d_in[5];
    const float* b3  = (const float*)d_in[6];
    float* out = (float*)d_out;
    float* T   = (float*)d_ws;
    unsigned short* IDX = (unsigned short*)((float*)d_ws + (TSZ + 1));
    int n = in_sizes[0];

    fused_build_kernel<<<(TSZ + 1 + 63) / 64, 256, 0, stream>>>(
        pw1, b1, pw2, b2, pw3, b3, T);
    build_idx_kernel<<<(BSZ + 1 + 255) / 256, 256, 0, stream>>>(T, IDX);
    bucket_apply_kernel<<<APPLY_BLOCKS, 256, 0, stream>>>(z, T, IDX, out, n);
}

// Round 8
// 85.500 us; speedup vs baseline: 1.2470x; 1.0513x over previous
//
#include <hip/hip_runtime.h>

// ModelInverse: invert monotone MLP CDF F(x) for 2M targets.
// R8: direct inverse-table apply (3 dispatches).
//  - fused_build: T[j] = A(j/TSZ) on 2^13+1 grid (unchanged from R7).
//  - invert_kernel: G[k] = F^-1(k/GSZ) on 2^14+1 uniform z-grid via exact
//    13-step binary search on L2-hot T + in-cell lerp (~1 us).
//  - apply: stage G (64 KB -> 2 blocks/CU) in LDS; per sample just
//    u = z*GSZ; lerp(G[k], G[k+1]).  2 LDS reads + ~8 VALU per sample,
//    no search, no divergent fix-up loops (R7 had ~6 LDS + ~25 VALU).
// Error: G-lerp err <= h^2*|G''|/8, G'' = -F''/F'^3 bounded ~1e6 in the
// transition region -> ~5e-4; saturated tail has F''->0. Well under the
// 0.0039 bf16 compare floor observed since R1.
//
// ws layout (floats): T[TSZ+1] @0 | G[GSZ+1] @8196 (16B aligned).

#define MONO 1e-3f
#define TLOG2 13
#define TSZ (1 << TLOG2)   // forward table: T[0..TSZ]
#define GLOG2 14
#define GSZ (1 << GLOG2)   // inverse table: G[0..GSZ]
#define WS_G 8196          // float offset of G in ws (TSZ+1=8193, pad to 16B)

typedef float fvec64 __attribute__((ext_vector_type(64)));

__device__ __forceinline__ float fast_rcp(float x) {
#if __has_builtin(__builtin_amdgcn_rcpf)
    return __builtin_amdgcn_rcpf(x);   // v_rcp_f32, ~1 ulp
#else
    return 1.0f / x;
#endif
}

__device__ __forceinline__ float sigmoidf_(float t) {
    return fast_rcp(1.0f + __expf(-t));   // v_mul+v_exp+v_add+v_rcp
}

// T[j] = sigmoid(w3 . sigmoid(W2 . sigmoid(x*w1+b1) + b2) + b3) + MONO*x
// Block = 256 = 4 waves; wave `sub` handles rows [16*sub, 16*sub+16) for 64
// entries (lane = entry). exp(pw2) staged into LDS by the whole block.
__global__ __launch_bounds__(256, 4) void fused_build_kernel(
        const float* __restrict__ pw1,
        const float* __restrict__ b1,
        const float* __restrict__ pw2,
        const float* __restrict__ b2,
        const float* __restrict__ pw3,
        const float* __restrict__ b3,
        float* __restrict__ T) {
    __shared__ __align__(16) float W2s[4096];
    __shared__ float part[256];

    int tid  = threadIdx.x;
#pragma unroll
    for (int i = 0; i < 16; ++i) {
        int idx = tid + i * 256;
        W2s[idx] = __expf(pw2[idx]);
    }
    __syncthreads();

    int lane = tid & 63;
    int sub = __builtin_amdgcn_readfirstlane(tid >> 6);   // 0..3, SGPR
    int j = blockIdx.x * 64 + lane;
    int jc = j <= TSZ ? j : TSZ;
    float x = (float)jc * (1.0f / (float)TSZ);

    fvec64 h1;    // SSA vector: cannot be demoted/remat'd
#pragma unroll
    for (int k = 0; k < 64; ++k)
        h1[k] = sigmoidf_(fmaf(x, __expf(pw1[k]), b1[k]));

    float acc3 = 0.0f;
#pragma unroll
    for (int r = 0; r < 16; ++r) {
        int row = sub * 16 + r;        // uniform -> s_load / uniform ds addr
        float acc = b2[row];
        const float4* __restrict__ w4 =
            reinterpret_cast<const float4*>(&W2s[row * 64]);
#pragma unroll
        for (int q = 0; q < 16; ++q) { // ds_read_b128 broadcast
            float4 w = w4[q];
            acc = fmaf(w.x, h1[4 * q + 0], acc);
            acc = fmaf(w.y, h1[4 * q + 1], acc);
            acc = fmaf(w.z, h1[4 * q + 2], acc);
            acc = fmaf(w.w, h1[4 * q + 3], acc);
        }
        acc3 = fmaf(__expf(pw3[row]), sigmoidf_(acc), acc3);
    }

    part[sub * 64 + lane] = acc3;
    __syncthreads();
    if (tid < 64 && j <= TSZ) {
        float s = part[lane] + part[64 + lane] + part[128 + lane]
                + part[192 + lane] + b3[0];
        T[j] = sigmoidf_(s) + MONO * x;
    }
}

// G[k] = x with F(x) = k/GSZ: exact binary search on T + in-cell lerp.
__global__ __launch_bounds__(256) void invert_kernel(
        const float* __restrict__ T,
        float* __restrict__ G) {
    int k = blockIdx.x * blockDim.x + threadIdx.x;
    if (k > GSZ) return;
    float a0 = T[0];
    float a1 = T[TSZ];
    float zt = fmaf((float)k * (1.0f / (float)GSZ), a1 - a0, a0);

    int lo = 0;
#pragma unroll
    for (int s = TSZ >> 1; s >= 1; s >>= 1) {
        int c = lo + s;                // c <= TSZ-1
        if (T[c] <= zt) lo = c;
    }
    float tl = T[lo];
    float th = T[lo + 1];
    float d = th - tl;
    float t = (d > 1e-30f) ? (zt - tl) * fast_rcp(d) : 0.5f;
    t = fminf(fmaxf(t, 0.0f), 1.0f);
    G[k] = ((float)lo + t) * (1.0f / (float)TSZ);
}

#define APPLY_BLOCKS 512   // 64 KB LDS -> 2 blocks/CU

__global__ __launch_bounds__(256) void apply_kernel(
        const float* __restrict__ z,
        const float* __restrict__ G,
        float* __restrict__ out, int n) {
    __shared__ __align__(16) float Gs[GSZ + 4];
    int tid = threadIdx.x;
#pragma unroll
    for (int i = 0; i < (GSZ / 4) / 256; ++i) {      // 4096 float4s
        int idx = tid + i * 256;
        reinterpret_cast<float4*>(Gs)[idx] =
            reinterpret_cast<const float4*>(G)[idx];
    }
    if (tid == 0) Gs[GSZ] = G[GSZ];
    __syncthreads();

    int nv = n >> 2;
    int stride = gridDim.x * 256;
    for (int idx = blockIdx.x * 256 + tid; idx < nv; idx += stride) {
        float4 zz = reinterpret_cast<const float4*>(z)[idx];
        float4 oo;
        {
            float u = fminf(fmaxf(zz.x, 0.0f), 1.0f) * (float)GSZ;
            int k = (int)u; k = k > GSZ - 1 ? GSZ - 1 : k;
            oo.x = fmaf(u - (float)k, Gs[k + 1] - Gs[k], Gs[k]);
        }
        {
            float u = fminf(fmaxf(zz.y, 0.0f), 1.0f) * (float)GSZ;
            int k = (int)u; k = k > GSZ - 1 ? GSZ - 1 : k;
            oo.y = fmaf(u - (float)k, Gs[k + 1] - Gs[k], Gs[k]);
        }
        {
            float u = fminf(fmaxf(zz.z, 0.0f), 1.0f) * (float)GSZ;
            int k = (int)u; k = k > GSZ - 1 ? GSZ - 1 : k;
            oo.z = fmaf(u - (float)k, Gs[k + 1] - Gs[k], Gs[k]);
        }
        {
            float u = fminf(fmaxf(zz.w, 0.0f), 1.0f) * (float)GSZ;
            int k = (int)u; k = k > GSZ - 1 ? GSZ - 1 : k;
            oo.w = fmaf(u - (float)k, Gs[k + 1] - Gs[k], Gs[k]);
        }
        reinterpret_cast<float4*>(out)[idx] = oo;
    }
    int base = nv * 4;
    for (int t = base + blockIdx.x * 256 + tid; t < n; t += stride) {
        float u = fminf(fmaxf(z[t], 0.0f), 1.0f) * (float)GSZ;
        int k = (int)u; k = k > GSZ - 1 ? GSZ - 1 : k;
        out[t] = fmaf(u - (float)k, Gs[k + 1] - Gs[k], Gs[k]);
    }
}

extern "C" void kernel_launch(void* const* d_in, const int* in_sizes, int n_in,
                              void* d_out, int out_size, void* d_ws, size_t ws_size,
                              hipStream_t stream) {
    const float* z   = (const float*)d_in[0];
    const float* pw1 = (const float*)d_in[1];
    const float* b1  = (const float*)d_in[2];
    const float* pw2 = (const float*)d_in[3];
    const float* b2  = (const float*)d_in[4];
    const float* pw3 = (const float*)d_in[5];
    const float* b3  = (const float*)d_in[6];
    float* out = (float*)d_out;
    float* T   = (float*)d_ws;
    float* G   = (float*)d_ws + WS_G;
    int n = in_sizes[0];

    fused_build_kernel<<<(TSZ + 1 + 63) / 64, 256, 0, stream>>>(
        pw1, b1, pw2, b2, pw3, b3, T);
    invert_kernel<<<(GSZ + 1 + 255) / 256, 256, 0, stream>>>(T, G);
    apply_kernel<<<APPLY_BLOCKS, 256, 0, stream>>>(z, G, out, n);
}